// Round 1
// baseline (260.307 us; speedup 1.0000x reference)
//
#include <hip/hip_runtime.h>

#define BDIM 256
#define T 200
#define E 64

__global__ __launch_bounds__(BDIM, 4) void din_kernel(
    const int* __restrict__ query,
    const int* __restrict__ keys,
    const float* __restrict__ emb,
    const float* __restrict__ w1,
    const float* __restrict__ b1,
    const float* __restrict__ w2,
    const float* __restrict__ b2,
    const float* __restrict__ dw1,
    const float* __restrict__ db1,
    const float* __restrict__ dw2,
    const float* __restrict__ db2,
    const float* __restrict__ ow,
    const float* __restrict__ ob,
    float* __restrict__ out)
{
    // sBig serves two roles (separated by barriers):
    //   phase A: M[e][j] at stride 64 (e*64+j), 4096 floats
    //   phase C: per-lane weighted-k accumulator at stride 65 (conflict-free)
    __shared__ __align__(16) float sBig[64 * 65 + 4];
    __shared__ __align__(16) float sU[64];
    __shared__ __align__(16) float sQ[64];
    __shared__ __align__(16) float sW2[64];
    __shared__ float sRed[8];
    __shared__ float sInt[64];
    __shared__ float sD1[128];
    __shared__ float sD2[64];

    const int tid  = threadIdx.x;
    const int lane = tid & 63;
    const int wid  = tid >> 6;
    const int b    = blockIdx.x;

    // ---- load query embedding row into LDS ----
    const int qi = query[b];
    if (tid < 16) ((float4*)sQ)[tid] = ((const float4*)(emb + (size_t)qi * E))[tid];

    // ---- gather this lane's key row into registers (lane == t) ----
    float4 kreg[16];
    if (tid < T) {
        const int ki = keys[b * T + tid];
        const float4* kp = (const float4*)(emb + (size_t)ki * E);
        #pragma unroll
        for (int c = 0; c < 16; ++c) kreg[c] = kp[c];
    } else {
        #pragma unroll
        for (int c = 0; c < 16; ++c) kreg[c] = make_float4(0.f, 0.f, 0.f, 0.f);
    }
    if (tid < 64) sW2[tid] = w2[tid];
    __syncthreads();

    // ---- build M[e][j] = w1[64+e][j] - w1[128+e][j] + q[e]*w1[192+e][j] ----
    {
        const int j  = tid & 63;
        const int eq = tid >> 6;            // 4 groups of 16 e-rows
        #pragma unroll
        for (int eo = 0; eo < 16; ++eo) {
            const int e = eq * 16 + eo;
            sBig[e * 64 + j] = w1[(64 + e) * 64 + j] - w1[(128 + e) * 64 + j]
                             + sQ[e] * w1[(192 + e) * 64 + j];
        }
    }
    // ---- u[j] = b1[j] + sum_e q[e]*(w1[e][j] + w1[128+e][j]) ----
    if (tid < 64) {
        float a = b1[tid];
        #pragma unroll 4
        for (int e = 0; e < 64; ++e)
            a = fmaf(sQ[e], w1[e * 64 + tid] + w1[(128 + e) * 64 + tid], a);
        sU[tid] = a;
    }
    __syncthreads();

    // ---- attention score for this lane's t:  sc = b2 + sum_j relu(hpre[j])*w2[j]
    float sc = 0.f;
    #pragma unroll 1
    for (int jc = 0; jc < 16; ++jc) {
        float4 acc = *(const float4*)&sU[4 * jc];
        const float* mp = &sBig[4 * jc];
        #pragma unroll
        for (int c = 0; c < 16; ++c) {
            const float4 kv = kreg[c];
            const float4 m0 = *(const float4*)(mp + (4 * c + 0) * 64);
            const float4 m1 = *(const float4*)(mp + (4 * c + 1) * 64);
            const float4 m2 = *(const float4*)(mp + (4 * c + 2) * 64);
            const float4 m3 = *(const float4*)(mp + (4 * c + 3) * 64);
            acc.x = fmaf(kv.x, m0.x, acc.x);
            acc.y = fmaf(kv.x, m0.y, acc.y);
            acc.z = fmaf(kv.x, m0.z, acc.z);
            acc.w = fmaf(kv.x, m0.w, acc.w);
            acc.x = fmaf(kv.y, m1.x, acc.x);
            acc.y = fmaf(kv.y, m1.y, acc.y);
            acc.z = fmaf(kv.y, m1.z, acc.z);
            acc.w = fmaf(kv.y, m1.w, acc.w);
            acc.x = fmaf(kv.z, m2.x, acc.x);
            acc.y = fmaf(kv.z, m2.y, acc.y);
            acc.z = fmaf(kv.z, m2.z, acc.z);
            acc.w = fmaf(kv.z, m2.w, acc.w);
            acc.x = fmaf(kv.w, m3.x, acc.x);
            acc.y = fmaf(kv.w, m3.y, acc.y);
            acc.z = fmaf(kv.w, m3.z, acc.z);
            acc.w = fmaf(kv.w, m3.w, acc.w);
        }
        const float4 wv4 = *(const float4*)&sW2[4 * jc];
        sc = fmaf(fmaxf(acc.x, 0.f), wv4.x, sc);
        sc = fmaf(fmaxf(acc.y, 0.f), wv4.y, sc);
        sc = fmaf(fmaxf(acc.z, 0.f), wv4.z, sc);
        sc = fmaf(fmaxf(acc.w, 0.f), wv4.w, sc);
    }
    float score = (tid < T) ? (sc + b2[0]) : -1e30f;

    // ---- softmax over t (shuffle within wave, LDS across waves) ----
    float m = score;
    #pragma unroll
    for (int off = 32; off > 0; off >>= 1) m = fmaxf(m, __shfl_xor(m, off));
    if (lane == 0) sRed[wid] = m;
    __syncthreads();
    const float gmax = fmaxf(fmaxf(sRed[0], sRed[1]), fmaxf(sRed[2], sRed[3]));
    const float p = __expf(score - gmax);          // masked lanes -> 0
    float s = p;
    #pragma unroll
    for (int off = 32; off > 0; off >>= 1) s += __shfl_xor(s, off);
    if (lane == 0) sRed[4 + wid] = s;
    __syncthreads();
    const float gsum = sRed[4] + sRed[5] + sRed[6] + sRed[7];
    const float w = p / gsum;

    // ---- interest[e] = sum_t w[t]*k[t][e]  (k rows are in registers) ----
    // phased accumulation into stride-65 buffer (reuses sBig; bank-conflict-free)
    for (int r = 0; r < 4; ++r) {
        if (wid == r) {
            float* row = &sBig[lane * 65];
            if (r == 0) {
                #pragma unroll
                for (int c = 0; c < 16; ++c) {
                    row[4 * c + 0] = w * kreg[c].x;
                    row[4 * c + 1] = w * kreg[c].y;
                    row[4 * c + 2] = w * kreg[c].z;
                    row[4 * c + 3] = w * kreg[c].w;
                }
            } else {
                #pragma unroll
                for (int c = 0; c < 16; ++c) {
                    row[4 * c + 0] += w * kreg[c].x;
                    row[4 * c + 1] += w * kreg[c].y;
                    row[4 * c + 2] += w * kreg[c].z;
                    row[4 * c + 3] += w * kreg[c].w;
                }
            }
        }
        __syncthreads();
    }
    if (tid < 64) {
        float a = 0.f;
        #pragma unroll 8
        for (int l = 0; l < 64; ++l) a += sBig[l * 65 + tid];
        sInt[tid] = a;
    }
    __syncthreads();

    // ---- deep MLP: 64 -> 128 -> 64 -> 1 ----
    if (tid < 128) {
        float a = db1[tid];
        #pragma unroll 8
        for (int e = 0; e < 64; ++e) a = fmaf(sInt[e], dw1[e * 128 + tid], a);
        sD1[tid] = fmaxf(a, 0.f);
    }
    __syncthreads();
    if (tid < 64) {
        float a = db2[tid];
        #pragma unroll 8
        for (int i = 0; i < 128; ++i) a = fmaf(sD1[i], dw2[i * 64 + tid], a);
        sD2[tid] = fmaxf(a, 0.f);
    }
    __syncthreads();
    if (tid < 64) {
        float v = sD2[tid] * ow[tid];
        #pragma unroll
        for (int off = 32; off > 0; off >>= 1) v += __shfl_xor(v, off);
        if (tid == 0) out[b] = 1.f / (1.f + __expf(-(v + ob[0])));
    }
}

extern "C" void kernel_launch(void* const* d_in, const int* in_sizes, int n_in,
                              void* d_out, int out_size, void* d_ws, size_t ws_size,
                              hipStream_t stream) {
    const int*   query = (const int*)d_in[0];
    const int*   keys  = (const int*)d_in[1];
    const float* emb   = (const float*)d_in[2];
    const float* w1    = (const float*)d_in[3];
    const float* b1    = (const float*)d_in[4];
    const float* w2    = (const float*)d_in[5];
    const float* b2    = (const float*)d_in[6];
    const float* dw1   = (const float*)d_in[7];
    const float* db1   = (const float*)d_in[8];
    const float* dw2   = (const float*)d_in[9];
    const float* db2   = (const float*)d_in[10];
    const float* ow    = (const float*)d_in[11];
    const float* ob    = (const float*)d_in[12];
    float* out = (float*)d_out;
    const int B = in_sizes[0];

    din_kernel<<<B, BDIM, 0, stream>>>(query, keys, emb, w1, b1, w2, b2,
                                       dw1, db1, dw2, db2, ow, ob, out);
}

// Round 2
// 253.386 us; speedup vs baseline: 1.0273x; 1.0273x over previous
//
#include <hip/hip_runtime.h>

#define BDIM 256
#define T 200
#define E 64

__global__ __launch_bounds__(BDIM, 4) void din_kernel(
    const int* __restrict__ query,
    const int* __restrict__ keys,
    const float* __restrict__ emb,
    const float* __restrict__ w1,
    const float* __restrict__ b1,
    const float* __restrict__ w2,
    const float* __restrict__ b2,
    const float* __restrict__ dw1,
    const float* __restrict__ db1,
    const float* __restrict__ dw2,
    const float* __restrict__ db2,
    const float* __restrict__ ow,
    const float* __restrict__ ob,
    float* __restrict__ out)
{
    // sBig dual-use (barrier-separated):
    //   phase A (score): M[e][j] at stride 64, read as wave-broadcast float4
    //   phase C (interest): per-lane accum at stride 65 (conflict-free scalar)
    __shared__ __align__(16) float sBig[64 * 65];
    __shared__ __align__(16) float sU[64];
    __shared__ __align__(16) float sQ[64];
    __shared__ __align__(16) float sW2[64];
    __shared__ __align__(16) float sUP[256];
    __shared__ float sRed[8];
    __shared__ float sInt[64];
    __shared__ float sD1[128];
    __shared__ float sD2[64];

    const int tid  = threadIdx.x;
    const int lane = tid & 63;
    const int wid  = tid >> 6;
    const int b    = blockIdx.x;

    // ---- query embedding row -> LDS; small vectors -> LDS ----
    const int qi = query[b];
    if (tid < 16) ((float4*)sQ)[tid] = ((const float4*)(emb + (size_t)qi * E))[tid];
    if (tid < 64) sW2[tid] = w2[tid];
    const float b2v = b2[0];

    // clamped key index: lanes >= T compute garbage scores that get masked,
    // and their softmax weight is exactly 0, so clamping is safe.
    const int tclamp = (tid < T) ? tid : (T - 1);
    const int ki = keys[b * T + tclamp];
    const float4* __restrict__ kp = (const float4*)(emb + (size_t)ki * E);
    __syncthreads();

    // ---- build M[e][j] = w1[64+e][j] - w1[128+e][j] + q[e]*w1[192+e][j] ----
    {
        const int j  = tid & 63;
        const int eq = tid >> 6;            // 4 groups of 16 e-rows
        #pragma unroll
        for (int eo = 0; eo < 16; ++eo) {
            const int e = eq * 16 + eo;
            sBig[e * 64 + j] = w1[(64 + e) * 64 + j] - w1[(128 + e) * 64 + j]
                             + sQ[e] * w1[(192 + e) * 64 + j];
        }
    }
    // ---- u partials: u[j] = b1[j] + sum_e q[e]*(w1[e][j] + w1[128+e][j]) ----
    {
        const int j  = tid & 63;
        const int pt = tid >> 6;
        float a = 0.f;
        #pragma unroll
        for (int eo = 0; eo < 16; ++eo) {
            const int e = pt * 16 + eo;
            a = fmaf(sQ[e], w1[e * 64 + j] + w1[(128 + e) * 64 + j], a);
        }
        sUP[tid] = a;
    }
    __syncthreads();
    if (tid < 64)
        sU[tid] = b1[tid] + sUP[tid] + sUP[64 + tid] + sUP[128 + tid] + sUP[192 + tid];
    __syncthreads();

    // ---- score: per-lane h_pre row accumulated in VGPRs, k streamed ----
    float4 acc[16];
    #pragma unroll
    for (int jq = 0; jq < 16; ++jq) acc[jq] = ((const float4*)sU)[jq];

    float4 kv = kp[0];
    #pragma unroll 1
    for (int c = 0; c < 16; ++c) {
        float4 kn;
        if (c < 15) kn = kp[c + 1];           // software prefetch
        const float4* r0 = (const float4*)&sBig[(4 * c + 0) * 64];
        const float4* r1 = (const float4*)&sBig[(4 * c + 1) * 64];
        const float4* r2 = (const float4*)&sBig[(4 * c + 2) * 64];
        const float4* r3 = (const float4*)&sBig[(4 * c + 3) * 64];
        #pragma unroll
        for (int jq = 0; jq < 16; ++jq) {
            const float4 m0 = r0[jq];
            const float4 m1 = r1[jq];
            const float4 m2 = r2[jq];
            const float4 m3 = r3[jq];
            float4 a = acc[jq];
            a.x = fmaf(kv.x, m0.x, a.x);
            a.y = fmaf(kv.x, m0.y, a.y);
            a.z = fmaf(kv.x, m0.z, a.z);
            a.w = fmaf(kv.x, m0.w, a.w);
            a.x = fmaf(kv.y, m1.x, a.x);
            a.y = fmaf(kv.y, m1.y, a.y);
            a.z = fmaf(kv.y, m1.z, a.z);
            a.w = fmaf(kv.y, m1.w, a.w);
            a.x = fmaf(kv.z, m2.x, a.x);
            a.y = fmaf(kv.z, m2.y, a.y);
            a.z = fmaf(kv.z, m2.z, a.z);
            a.w = fmaf(kv.z, m2.w, a.w);
            a.x = fmaf(kv.w, m3.x, a.x);
            a.y = fmaf(kv.w, m3.y, a.y);
            a.z = fmaf(kv.w, m3.z, a.z);
            a.w = fmaf(kv.w, m3.w, a.w);
            acc[jq] = a;
        }
        kv = kn;
    }

    float sc = 0.f;
    #pragma unroll
    for (int jq = 0; jq < 16; ++jq) {
        const float4 wv = ((const float4*)sW2)[jq];
        sc = fmaf(fmaxf(acc[jq].x, 0.f), wv.x, sc);
        sc = fmaf(fmaxf(acc[jq].y, 0.f), wv.y, sc);
        sc = fmaf(fmaxf(acc[jq].z, 0.f), wv.z, sc);
        sc = fmaf(fmaxf(acc[jq].w, 0.f), wv.w, sc);
    }
    const float score = (tid < T) ? (sc + b2v) : -1e30f;

    // ---- softmax over t ----
    float m = score;
    #pragma unroll
    for (int off = 32; off > 0; off >>= 1) m = fmaxf(m, __shfl_xor(m, off));
    if (lane == 0) sRed[wid] = m;
    __syncthreads();
    const float gmax = fmaxf(fmaxf(sRed[0], sRed[1]), fmaxf(sRed[2], sRed[3]));
    const float p = __expf(score - gmax);      // masked lanes -> 0
    float s = p;
    #pragma unroll
    for (int off = 32; off > 0; off >>= 1) s += __shfl_xor(s, off);
    if (lane == 0) sRed[4 + wid] = s;
    __syncthreads();
    const float gsum = sRed[4] + sRed[5] + sRed[6] + sRed[7];
    const float w = p / gsum;

    // ---- interest[e] = sum_t w[t]*k[t][e]; k reloaded (L2-hot), w=0 pads ----
    for (int r = 0; r < 4; ++r) {
        if (wid == r) {
            float* row = &sBig[lane * 65];
            #pragma unroll
            for (int c = 0; c < 16; ++c) {
                const float4 kv2 = kp[c];
                if (r == 0) {
                    row[4 * c + 0] = w * kv2.x;
                    row[4 * c + 1] = w * kv2.y;
                    row[4 * c + 2] = w * kv2.z;
                    row[4 * c + 3] = w * kv2.w;
                } else {
                    row[4 * c + 0] += w * kv2.x;
                    row[4 * c + 1] += w * kv2.y;
                    row[4 * c + 2] += w * kv2.z;
                    row[4 * c + 3] += w * kv2.w;
                }
            }
        }
        __syncthreads();
    }
    if (tid < 64) {
        float a = 0.f;
        #pragma unroll 8
        for (int l = 0; l < 64; ++l) a += sBig[l * 65 + tid];
        sInt[tid] = a;
    }
    __syncthreads();

    // ---- deep MLP: 64 -> 128 -> 64 -> 1 ----
    if (tid < 128) {
        float a = db1[tid];
        #pragma unroll 8
        for (int e = 0; e < 64; ++e) a = fmaf(sInt[e], dw1[e * 128 + tid], a);
        sD1[tid] = fmaxf(a, 0.f);
    }
    __syncthreads();
    if (tid < 64) {
        float a = db2[tid];
        #pragma unroll 8
        for (int i = 0; i < 128; ++i) a = fmaf(sD1[i], dw2[i * 64 + tid], a);
        sD2[tid] = fmaxf(a, 0.f);
    }
    __syncthreads();
    if (tid < 64) {
        float v = sD2[tid] * ow[tid];
        #pragma unroll
        for (int off = 32; off > 0; off >>= 1) v += __shfl_xor(v, off);
        if (tid == 0) out[b] = 1.f / (1.f + __expf(-(v + ob[0])));
    }
}

extern "C" void kernel_launch(void* const* d_in, const int* in_sizes, int n_in,
                              void* d_out, int out_size, void* d_ws, size_t ws_size,
                              hipStream_t stream) {
    const int*   query = (const int*)d_in[0];
    const int*   keys  = (const int*)d_in[1];
    const float* emb   = (const float*)d_in[2];
    const float* w1    = (const float*)d_in[3];
    const float* b1    = (const float*)d_in[4];
    const float* w2    = (const float*)d_in[5];
    const float* b2    = (const float*)d_in[6];
    const float* dw1   = (const float*)d_in[7];
    const float* db1   = (const float*)d_in[8];
    const float* dw2   = (const float*)d_in[9];
    const float* db2   = (const float*)d_in[10];
    const float* ow    = (const float*)d_in[11];
    const float* ob    = (const float*)d_in[12];
    float* out = (float*)d_out;
    const int B = in_sizes[0];

    din_kernel<<<B, BDIM, 0, stream>>>(query, keys, emb, w1, b1, w2, b2,
                                       dw1, db1, dw2, db2, ow, ob, out);
}